// Round 10
// baseline (688.434 us; speedup 1.0000x reference)
//
#include <hip/hip_runtime.h>
#include <hip/hip_bf16.h>

typedef __hip_bfloat16 bf16;
using bf16x8 = __attribute__((ext_vector_type(8))) short;
using f32x4  = __attribute__((ext_vector_type(4))) float;

#define S_LEN 1024
#define CDIM  576
#define NHEAD 8
#define DKH   72
#define BATCH 4
#define MROWS 4096   // B*S
#define FFDIM 2304
#define QKVN  1728   // 3*C

// async global->LDS, 16B per lane, lane-ordered LDS destination
__device__ __forceinline__ void gload16(const void* g, void* l) {
  __builtin_amdgcn_global_load_lds(
      (const __attribute__((address_space(1))) unsigned int*)g,
      (__attribute__((address_space(3))) unsigned int*)l, 16, 0, 0);
}

// counted vmcnt wait (literal immediates; "memory" = IR-level fence)
template <int N> __device__ __forceinline__ void wait_vmcnt() {
  if constexpr (N == 0)      asm volatile("s_waitcnt vmcnt(0)" ::: "memory");
  else if constexpr (N == 8) asm volatile("s_waitcnt vmcnt(8)" ::: "memory");
}

// float -> bf16 bits (RNE), pure integer math (type-safe for LDS punning)
__device__ __forceinline__ short f2bf_bits(float x) {
  unsigned int u = __float_as_uint(x);
  u += 0x7fffu + ((u >> 16) & 1u);
  return (short)(u >> 16);
}

// ---------------- weight transpose + fp32->bf16 convert ----------------
__global__ __launch_bounds__(256) void transpose_cvt(
    const float* __restrict__ in, bf16* __restrict__ out, int K, int N,
    size_t in_ls, size_t out_ls) {
  __shared__ float tile[32][33];
  const float* inl = in + (size_t)blockIdx.z * in_ls;
  bf16* outl = out + (size_t)blockIdx.z * out_ls;
  int n0 = blockIdx.x * 32, k0 = blockIdx.y * 32;
  int tx = threadIdx.x & 31, ty = threadIdx.x >> 5;   // ty 0..7
#pragma unroll
  for (int i = 0; i < 32; i += 8)
    tile[ty + i][tx] = inl[(size_t)(k0 + ty + i) * N + (n0 + tx)];
  __syncthreads();
#pragma unroll
  for (int i = 0; i < 32; i += 8)
    outl[(size_t)(n0 + ty + i) * K + (k0 + tx)] = __float2bfloat16(tile[tx][ty + i]);
}

// ---------------- xf = right_shift(x) + pos ----------------
__global__ __launch_bounds__(256) void build_xf(
    const float* __restrict__ x, const float* __restrict__ p0,
    const float* __restrict__ p1, const float* __restrict__ p2,
    float* __restrict__ xf) {
  int idx = blockIdx.x * 256 + threadIdx.x;      // one float4 per thread
  int c4 = idx % 144;
  int s  = (idx / 144) & (S_LEN - 1);
  int b  = idx / (144 * S_LEN);
  int c  = c4 * 4;
  int t = s >> 8, hh = (s >> 4) & 15, w = s & 15;
  float4 pv;
  if (c < 192)       pv = *(const float4*)&p0[t  * 192 + c];
  else if (c < 384)  pv = *(const float4*)&p1[hh * 192 + c - 192];
  else               pv = *(const float4*)&p2[w  * 192 + c - 384];
  float4 xv = make_float4(0.f, 0.f, 0.f, 0.f);
  if (s > 0) xv = *(const float4*)&x[((size_t)b * S_LEN + s - 1) * CDIM + c];
  float4 r = make_float4(xv.x + pv.x, xv.y + pv.y, xv.z + pv.z, xv.w + pv.w);
  *(float4*)&xf[((size_t)b * S_LEN + s) * CDIM + c] = r;
}

// ---------------- LayerNorm (eps added to rsqrt, per reference) ----------------
__global__ __launch_bounds__(256) void ln_kernel(
    const float* __restrict__ x, const float* __restrict__ g,
    const float* __restrict__ b, bf16* __restrict__ out) {
  int row  = blockIdx.x * 4 + (threadIdx.x >> 6);
  int lane = threadIdx.x & 63;
  const float* xr = x + (size_t)row * CDIM;
  float vals[9];
  float sum = 0.f;
#pragma unroll
  for (int i = 0; i < 9; i++) { vals[i] = xr[lane + 64 * i]; sum += vals[i]; }
#pragma unroll
  for (int o = 1; o < 64; o <<= 1) sum += __shfl_xor(sum, o);
  float mu = sum * (1.f / CDIM);
  float vs = 0.f;
#pragma unroll
  for (int i = 0; i < 9; i++) { float d = vals[i] - mu; vs += d * d; }
#pragma unroll
  for (int o = 1; o < 64; o <<= 1) vs += __shfl_xor(vs, o);
  float mult = 1e-5f + rsqrtf(vs * (1.f / CDIM));
  bf16* orow = out + (size_t)row * CDIM;
#pragma unroll
  for (int i = 0; i < 9; i++) {
    int c = lane + 64 * i;
    orow[c] = __float2bfloat16((vals[i] - mu) * mult * g[c] + b[c]);
  }
}

// ---------------- GEMM v9: barrier-free wave-autonomous 64x64 tiles ----------
// FIX from v8 (failed): a 64x64 wave tile needs acc[4][4] (fragment-repeat
// MI=NI=4), 16 MFMA / K-step, epilogue spanning all 4x4 frags. v8's acc[2][2]
// covered only the 32x32 corner (m225/m226-class decomposition bug).
// Each wave owns one 64x64 tile with PRIVATE double-buffered LDS: zero
// barriers, zero cross-wave coupling. Per iter: stage tile t+1 (8 gloads) ->
// vmcnt(8) (tile t landed; in-order per-wave retirement) -> 8 ds_read_b128 ->
// 16 MFMA. sched_barrier(0) after the wait (no ds_read hoisting) and at loop
// end (no next-iter gload hoisting above this iter's ds_reads / software
// pipelining across the backedge). LDS [64][32] bf16 linear: b128 conflict
// floor (8 dword-accesses/bank). 64KB/block -> 2 blocks/CU, 8 self-paced
// waves/CU. Block = 4 consecutive m-tiles sharing the B panel (L2 locality).
template <bool BIAS, bool RES, int ACT, bool OUTBF>
__global__ __launch_bounds__(256) void gemm4(
    const bf16* __restrict__ A, const bf16* __restrict__ Bt,
    const float* __restrict__ bias, const float* __restrict__ res,
    void* __restrict__ outp, int N, int K) {
  __shared__ __align__(16) short lds[4][2][2][2048];  // [wave][buf][A/B][64*32]
  const int tid = threadIdx.x, lane = tid & 63, wave = tid >> 6;
  const int lr = lane & 15, quad = lane >> 4;
  const int g = blockIdx.x * 4 + wave;     // wave-tile index
  const int mt = g & 63, nt = g >> 6;      // M/64 == 64 tiles always
  const int m0 = mt * 64, n0 = nt * 64;
  f32x4 acc[4][4] = {};

  const int srow = lane >> 2, scol = (lane & 3) * 8;  // staging: 16 rows x 32 cols per gload
  const short* Ag[4];
  const short* Bg[4];
#pragma unroll
  for (int j = 0; j < 4; j++) {
    Ag[j] = (const short*)A  + (size_t)(m0 + j * 16 + srow) * K + scol;
    Bg[j] = (const short*)Bt + (size_t)(n0 + j * 16 + srow) * K + scol;
  }

  const int T = K / 32;
  // prologue: stage tile 0 into buf 0
#pragma unroll
  for (int j = 0; j < 4; j++) gload16(Ag[j], &lds[wave][0][0][j * 512]);
#pragma unroll
  for (int j = 0; j < 4; j++) gload16(Bg[j], &lds[wave][0][1][j * 512]);

  int cur = 0;
  for (int t = 0; t < T; ++t, cur ^= 1) {
    if (t + 1 < T) {
      const int nxt = cur ^ 1, k1 = (t + 1) * 32;
#pragma unroll
      for (int j = 0; j < 4; j++) gload16(Ag[j] + k1, &lds[wave][nxt][0][j * 512]);
#pragma unroll
      for (int j = 0; j < 4; j++) gload16(Bg[j] + k1, &lds[wave][nxt][1][j * 512]);
      wait_vmcnt<8>();                     // tile t landed; t+1 in flight
    } else {
      wait_vmcnt<0>();                     // final tile
    }
    __builtin_amdgcn_sched_barrier(0);     // reads stay below the wait
    bf16x8 af[4], bfv[4];
#pragma unroll
    for (int mi = 0; mi < 4; mi++)
      af[mi] = *(const bf16x8*)&lds[wave][cur][0][(mi * 16 + lr) * 32 + quad * 8];
#pragma unroll
    for (int ni = 0; ni < 4; ni++)
      bfv[ni] = *(const bf16x8*)&lds[wave][cur][1][(ni * 16 + lr) * 32 + quad * 8];
#pragma unroll
    for (int mi = 0; mi < 4; mi++)
#pragma unroll
      for (int ni = 0; ni < 4; ni++)
        acc[mi][ni] = __builtin_amdgcn_mfma_f32_16x16x32_bf16(af[mi], bfv[ni], acc[mi][ni], 0, 0, 0);
    __builtin_amdgcn_sched_barrier(0);     // next-iter gloads stay below this iter's reads
  }

  float* fout = (float*)outp;
  bf16*  bout = (bf16*)outp;
#pragma unroll
  for (int mi = 0; mi < 4; mi++)
#pragma unroll
    for (int ni = 0; ni < 4; ni++) {
      int col = n0 + ni * 16 + lr;
#pragma unroll
      for (int r = 0; r < 4; r++) {
        int row = m0 + mi * 16 + quad * 4 + r;
        float v = acc[mi][ni][r];
        if (BIAS) v += bias[col];
        if (ACT == 1) v = v / (1.f + __expf(-1.702f * v));   // GeLU2
        size_t idx = (size_t)row * N + col;
        if (RES) v += res[idx];
        if (OUTBF) bout[idx] = __float2bfloat16(v);
        else       fout[idx] = v;
      }
    }
}

// ---------------- MFMA flash attention v5: defer-max + post-PV reduce --------
__global__ __launch_bounds__(256) void attn_mfma(
    const bf16* __restrict__ qkv, bf16* __restrict__ a) {
  __shared__ __align__(16) short ldsK[2][9 * 512];   // pages: w*2+c (c=0,1), 8=col64 page
  __shared__ __align__(16) short ldsVt[2][80][104];  // [d][key], padded rows
  __shared__ __align__(16) short ldsP[4 * 1024];     // per-wave, fragment-linear
  const int bh = blockIdx.y, b = bh >> 3, h = bh & 7;
  const int tid = threadIdx.x, wave = tid >> 6, lane = tid & 63;
  const int lr = lane & 15, quad = lane >> 4;
  const int qt = (blockIdx.y < 16) ? (15 - (int)blockIdx.x) : (int)blockIdx.x;
  const float scale = 0.11785113019775793f;  // 1/sqrt(72)
  const int qcol = h * DKH, kcol = CDIM + h * DKH, vcol = 2 * CDIM + h * DKH;

  const int qrow = qt * 64 + wave * 16 + lr;
  const short* qg = (const short*)qkv + (size_t)(b * S_LEN + qrow) * QKVN + qcol;
  bf16x8 qfrag[3];
#pragma unroll
  for (int c = 0; c < 3; c++) {
    int d0 = c * 32 + quad * 8;
    bf16x8 z = {0, 0, 0, 0, 0, 0, 0, 0};
    qfrag[c] = (d0 < DKH) ? *(const bf16x8*)(qg + d0) : z;
  }
  f32x4 oacc[5] = {};
  float m[4], l[4];
#pragma unroll
  for (int r = 0; r < 4; r++) { m[r] = -1e30f; l[r] = 0.f; }

  // staging bases (advance by kt*64*QKVN)
  const size_t ktstep = (size_t)64 * QKVN;
  const short* kg0 = (const short*)qkv + (size_t)(b * S_LEN + wave * 16 + lr) * QKVN + kcol + quad * 8;
  const short* kg2 = (const short*)qkv + (size_t)(b * S_LEN + lane) * QKVN + kcol + 64;  // wave0 page-8
  const int vkey = tid & 63, vdgb = tid >> 6;
  const short* vg0 = (const short*)qkv + (size_t)(b * S_LEN + vkey) * QKVN + vcol;

  // ---- prologue: stage kt=0 into buf 0 ----
  {
#pragma unroll
    for (int c = 0; c < 2; c++)
      gload16(kg0 + c * 32, &ldsK[0][(wave * 2 + c) * 512]);
    if (wave == 0) gload16(kg2, &ldsK[0][8 * 512]);
#pragma unroll
    for (int pass = 0; pass < 3; pass++) {
      int d0 = (vdgb + pass * 4) * 8;  // 0..88
      if (d0 < 80) {
        bf16x8 vv = {0, 0, 0, 0, 0, 0, 0, 0};
        if (d0 < DKH) vv = *(const bf16x8*)(vg0 + d0);
#pragma unroll
        for (int j = 0; j < 8; j++) ldsVt[0][d0 + j][vkey] = vv[j];
      }
    }
  }
  __syncthreads();

  for (int kt = 0; kt <= qt; kt++) {
    const int cur = kt & 1, nxt = cur ^ 1;
    const bool pf = (kt < qt);
    bf16x8 vpre[3];
    if (pf) {
      const short* kg = kg0 + (size_t)(kt + 1) * ktstep;
#pragma unroll
      for (int c = 0; c < 2; c++)
        gload16(kg + c * 32, &ldsK[nxt][(wave * 2 + c) * 512]);
      if (wave == 0) gload16(kg2 + (size_t)(kt + 1) * ktstep, &ldsK[nxt][8 * 512]);
      const short* vg = vg0 + (size_t)(kt + 1) * ktstep;
#pragma unroll
      for (int pass = 0; pass < 3; pass++) {
        int d0 = (vdgb + pass * 4) * 8;
        bf16x8 z = {0, 0, 0, 0, 0, 0, 0, 0};
        vpre[pass] = (d0 < DKH) ? *(const bf16x8*)(vg + d0) : z;
      }
    }
    // ---- QK^T ----
    f32x4 sacc[4] = {};
    __builtin_amdgcn_s_setprio(1);
#pragma unroll
    for (int nc = 0; nc < 4; nc++) {
      bf16x8 kf0 = *(const bf16x8*)&ldsK[cur][(nc * 2 + 0) * 512 + lane * 8];
      sacc[nc] = __builtin_amdgcn_mfma_f32_16x16x32_bf16(qfrag[0], kf0, sacc[nc], 0, 0, 0);
      bf16x8 kf1 = *(const bf16x8*)&ldsK[cur][(nc * 2 + 1) * 512 + lane * 8];
      sacc[nc] = __builtin_amdgcn_mfma_f32_16x16x32_bf16(qfrag[1], kf1, sacc[nc], 0, 0, 0);
      bf16x8 kf2 = *(const bf16x8*)&ldsK[cur][8 * 512 + (nc * 16 + lr) * 8];
      sacc[nc] = __builtin_amdgcn_mfma_f32_16x16x32_bf16(qfrag[2], kf2, sacc[nc], 0, 0, 0);
    }
    __builtin_amdgcn_s_setprio(0);
    // ---- scale + causal mask + per-lane local max (no reduce) ----
    float pmax[4];
#pragma unroll
    for (int r = 0; r < 4; r++) pmax[r] = -1e30f;
    bool diag = (kt == qt);
#pragma unroll
    for (int nc = 0; nc < 4; nc++)
#pragma unroll
      for (int r = 0; r < 4; r++) {
        float s = sacc[nc][r] * scale;
        if (diag && (nc * 16 + lr > wave * 16 + quad * 4 + r)) s = -1e30f;
        sacc[nc][r] = s;
        pmax[r] = fmaxf(pmax[r], s);
      }
    // ---- T13 defer-max: rescale only when some lane exceeds m+8 ----
    bool within = (pmax[0] - m[0] <= 8.f) && (pmax[1] - m[1] <= 8.f) &&
                  (pmax[2] - m[2] <= 8.f) && (pmax[3] - m[3] <= 8.f);
    if (!__all(within)) {
      float tmax[4];
#pragma unroll
      for (int r = 0; r < 4; r++) {
        tmax[r] = pmax[r];
        tmax[r] = fmaxf(tmax[r], __shfl_xor(tmax[r], 1));
        tmax[r] = fmaxf(tmax[r], __shfl_xor(tmax[r], 2));
        tmax[r] = fmaxf(tmax[r], __shfl_xor(tmax[r], 4));
        tmax[r] = fmaxf(tmax[r], __shfl_xor(tmax[r], 8));
      }
#pragma unroll
      for (int r = 0; r < 4; r++) {
        float mn = fmaxf(m[r], tmax[r]);
        float alpha = __expf(m[r] - mn);
        m[r] = mn;
        l[r] *= alpha;
#pragma unroll
        for (int dc = 0; dc < 5; dc++) oacc[dc][r] *= alpha;
      }
    }
    // ---- P = exp(s - m), write fragment-linear to ldsP ----
    float psum[4];
#pragma unroll
    for (int r = 0; r < 4; r++) psum[r] = 0.f;
#pragma unroll
    for (int nc = 0; nc < 4; nc++)
#pragma unroll
      for (int r = 0; r < 4; r++) {
        float p = __expf(sacc[nc][r] - m[r]);
        psum[r] += p;
        int col = nc * 16 + lr;
        ldsP[wave * 1024 + (col >> 5) * 512 +
             (((col >> 3) & 3) * 16 + quad * 4 + r) * 8 + (col & 7)] = f2bf_bits(p);
      }
    // ---- PV (P-write -> pfrag-read RAW is compiler-tracked lgkmcnt) ----
    bf16x8 pfrag[2];
#pragma unroll
    for (int kc = 0; kc < 2; kc++)
      pfrag[kc] = *(const bf16x8*)&ldsP[wave * 1024 + kc * 512 + lane * 8];
    __builtin_amdgcn_s_setprio(1);
#pragma unroll
    for (int dc = 0; dc < 5; dc++)
#pragma unroll
      for (int kc = 0; kc < 2; kc++) {
        bf16x8 vf = *(const bf16x8*)&ldsVt[cur][dc * 16 + lr][kc * 32 + quad * 8];
        oacc[dc] = __builtin_amdgcn_mfma_f32_16x16x32_bf16(pfrag[kc], vf, oacc[dc], 0, 0, 0);
      }
    __builtin_amdgcn_s_setprio(0);
    // ---- psum reduce + l update (after PV, off the critical path) ----
#pragma unroll
    for (int r = 0; r < 4; r++) {
      psum[r] += __shfl_xor(psum[r], 1);
      psum[r] += __shfl_xor(psum[r], 2);
      psum[r] += __shfl_xor(psum[r], 4);
      psum[r] += __shfl_xor(psum[r], 8);
      l[r] += psum[r];
    }
    // ---- late V write (prefetched regs -> ldsVt[nxt]) ----
    if (pf) {
#pragma unroll
      for (int pass = 0; pass < 3; pass++) {
        int d0 = (vdgb + pass * 4) * 8;
        if (d0 < 80) {
#pragma unroll
          for (int j = 0; j < 8; j++) ldsVt[nxt][d0 + j][vkey] = vpre[pass][j];
        }
      }
    }
    __syncthreads();
  }  // kt

#pragma unroll
  for (int dc = 0; dc < 5; dc++) {
    int d = dc * 16 + lr;
    if (d < DKH) {
#pragma unroll
      for (int r = 0; r < 4; r++) {
        int row = qt * 64 + wave * 16 + quad * 4 + r;
        float val = oacc[dc][r] / l[r];
        a[(size_t)(b * S_LEN + row) * CDIM + h * DKH + d] = __float2bfloat16(val);
      }
    }
  }
}

// ---------------- launch ----------------
extern "C" void kernel_launch(void* const* d_in, const int* in_sizes, int n_in,
                              void* d_out, int out_size, void* d_ws, size_t ws_size,
                              hipStream_t stream) {
  const float* x    = (const float*)d_in[0];
  const float* pos0 = (const float*)d_in[1];
  const float* pos1 = (const float*)d_in[2];
  const float* pos2 = (const float*)d_in[3];
  const float* ln1g = (const float*)d_in[4];
  const float* ln1b = (const float*)d_in[5];
  const float* wq   = (const float*)d_in[6];
  const float* wk   = (const float*)d_in[7];
  const float* wv   = (const float*)d_in[8];
  const float* wo   = (const float*)d_in[9];
  const float* wob  = (const float*)d_in[10];
  const float* ln2g = (const float*)d_in[11];
  const float* ln2b = (const float*)d_in[12];
  const float* w1   = (const float*)d_in[13];
  const float* b1   = (const float*)d_in[14];
  const float* w2   = (const float*)d_in[15];
  const float* b2   = (const float*)d_in[16];

  char* ws = (char*)d_ws;
  size_t off = 0;
  auto alloc = [&](size_t bytes) {
    char* p = ws + off;
    off += (bytes + 255) & ~(size_t)255;
    return p;
  };
  bf16* wqkvT = (bf16*)alloc((size_t)4 * QKVN * CDIM * sizeof(bf16));
  bf16* woT   = (bf16*)alloc((size_t)4 * CDIM * CDIM * sizeof(bf16));
  bf16* w1T   = (bf16*)alloc((size_t)4 * FFDIM * CDIM * sizeof(bf16));
  bf16* w2T   = (bf16*)alloc((size_t)4 * CDIM * FFDIM * sizeof(bf16));
  bf16* hbuf  = (bf16*)alloc((size_t)MROWS * CDIM * sizeof(bf16));
  bf16* abuf  = (bf16*)alloc((size_t)MROWS * CDIM * sizeof(bf16));
  bf16* ubuf  = (bf16*)alloc((size_t)MROWS * FFDIM * sizeof(bf16));
  bf16* qkvb  = (bf16*)alloc((size_t)MROWS * QKVN * sizeof(bf16));
  float* xf   = (float*)d_out;   // residual stream lives in d_out (fp32)

  const size_t ils  = (size_t)CDIM * CDIM;
  const size_t ils2 = (size_t)CDIM * FFDIM;
  const size_t qkv_ls = (size_t)QKVN * CDIM;
  transpose_cvt<<<dim3(18, 18, 4), 256, 0, stream>>>(wq, wqkvT, CDIM, CDIM, ils, qkv_ls);
  transpose_cvt<<<dim3(18, 18, 4), 256, 0, stream>>>(wk, wqkvT + (size_t)CDIM * CDIM, CDIM, CDIM, ils, qkv_ls);
  transpose_cvt<<<dim3(18, 18, 4), 256, 0, stream>>>(wv, wqkvT + (size_t)2 * CDIM * CDIM, CDIM, CDIM, ils, qkv_ls);
  transpose_cvt<<<dim3(18, 18, 4), 256, 0, stream>>>(wo, woT, CDIM, CDIM, ils, ils);
  transpose_cvt<<<dim3(72, 18, 4), 256, 0, stream>>>(w1, w1T, CDIM, FFDIM, ils2, ils2);
  transpose_cvt<<<dim3(18, 72, 4), 256, 0, stream>>>(w2, w2T, FFDIM, CDIM, ils2, ils2);

  build_xf<<<2304, 256, 0, stream>>>(x, pos0, pos1, pos2, xf);

  for (int l = 0; l < 4; l++) {
    bf16* wqkv_l = wqkvT + (size_t)l * qkv_ls;
    bf16* wo_l   = woT   + (size_t)l * ils;
    bf16* w1_l   = w1T   + (size_t)l * ils2;
    bf16* w2_l   = w2T   + (size_t)l * ils2;

    ln_kernel<<<1024, 256, 0, stream>>>(xf, ln1g + l * CDIM, ln1b + l * CDIM, hbuf);
    // fused QKV: [4096,576] x [1728,576]^T -> qkvb (64x64 wave-tiles, 432 blocks)
    gemm4<false, false, 0, true><<<dim3(64 * (QKVN / 64) / 4), 256, 0, stream>>>(
        hbuf, wqkv_l, nullptr, nullptr, qkvb, QKVN, CDIM);
    attn_mfma<<<dim3(16, 32), 256, 0, stream>>>(qkvb, abuf);
    // proj + bias + residual -> xf (144 blocks)
    gemm4<true, true, 0, false><<<dim3(64 * (CDIM / 64) / 4), 256, 0, stream>>>(
        abuf, wo_l, wob + l * CDIM, xf, xf, CDIM, CDIM);
    ln_kernel<<<1024, 256, 0, stream>>>(xf, ln2g + l * CDIM, ln2b + l * CDIM, hbuf);
    // FFN1 + bias + GeLU2 -> ubuf (576 blocks)
    gemm4<true, false, 1, true><<<dim3(64 * (FFDIM / 64) / 4), 256, 0, stream>>>(
        hbuf, w1_l, b1 + l * FFDIM, nullptr, ubuf, FFDIM, CDIM);
    // FFN2 + bias + residual -> xf (144 blocks)
    gemm4<true, true, 0, false><<<dim3(64 * (CDIM / 64) / 4), 256, 0, stream>>>(
        ubuf, w2_l, b2 + l * CDIM, xf, xf, CDIM, FFDIM);
  }
}

// Round 11
// 670.182 us; speedup vs baseline: 1.0272x; 1.0272x over previous
//
#include <hip/hip_runtime.h>
#include <hip/hip_bf16.h>

typedef __hip_bfloat16 bf16;
using bf16x8 = __attribute__((ext_vector_type(8))) short;
using f32x4  = __attribute__((ext_vector_type(4))) float;

#define S_LEN 1024
#define CDIM  576
#define NHEAD 8
#define DKH   72
#define BATCH 4
#define MROWS 4096   // B*S
#define FFDIM 2304
#define QKVN  1728   // 3*C

// async global->LDS, 16B per lane, lane-ordered LDS destination
__device__ __forceinline__ void gload16(const void* g, void* l) {
  __builtin_amdgcn_global_load_lds(
      (const __attribute__((address_space(1))) unsigned int*)g,
      (__attribute__((address_space(3))) unsigned int*)l, 16, 0, 0);
}

// counted vmcnt wait (literal immediates; "memory" = IR-level fence)
template <int N> __device__ __forceinline__ void wait_vmcnt() {
  if constexpr (N == 0)      asm volatile("s_waitcnt vmcnt(0)" ::: "memory");
  else if constexpr (N == 2) asm volatile("s_waitcnt vmcnt(2)" ::: "memory");
  else if constexpr (N == 3) asm volatile("s_waitcnt vmcnt(3)" ::: "memory");
  else if constexpr (N == 4) asm volatile("s_waitcnt vmcnt(4)" ::: "memory");
  else if constexpr (N == 6) asm volatile("s_waitcnt vmcnt(6)" ::: "memory");
}

// float -> bf16 bits (RNE), pure integer math (type-safe for LDS punning)
__device__ __forceinline__ short f2bf_bits(float x) {
  unsigned int u = __float_as_uint(x);
  u += 0x7fffu + ((u >> 16) & 1u);
  return (short)(u >> 16);
}

// ---------------- fused prologue: 6 weight transposes + build_xf, ONE dispatch ----
// Block ranges (all branches block-uniform):
//   [0,1296)      wq   (18x18x4)     [1296,2592)  wk
//   [2592,3888)   wv                 [3888,5184)  wo
//   [5184,10368)  w1   (72x18x4)     [10368,15552) w2 (18x72x4)
//   [15552,17856) build_xf (2304 blocks)
__device__ __forceinline__ void transpose_body(
    float (*tile)[33], const float* in, bf16* out, int K, int N,
    size_t in_ls, size_t out_ls, int bx, int by, int z) {
  const float* inl = in + (size_t)z * in_ls;
  bf16* outl = out + (size_t)z * out_ls;
  int n0 = bx * 32, k0 = by * 32;
  int tx = threadIdx.x & 31, ty = threadIdx.x >> 5;   // ty 0..7
#pragma unroll
  for (int i = 0; i < 32; i += 8)
    tile[ty + i][tx] = inl[(size_t)(k0 + ty + i) * N + (n0 + tx)];
  __syncthreads();
#pragma unroll
  for (int i = 0; i < 32; i += 8)
    outl[(size_t)(n0 + ty + i) * K + (k0 + tx)] = __float2bfloat16(tile[tx][ty + i]);
}

__global__ __launch_bounds__(256) void prologue(
    const float* __restrict__ wq, const float* __restrict__ wk,
    const float* __restrict__ wv, const float* __restrict__ wo,
    const float* __restrict__ w1, const float* __restrict__ w2,
    bf16* __restrict__ wqkvT, bf16* __restrict__ woT,
    bf16* __restrict__ w1T, bf16* __restrict__ w2T,
    const float* __restrict__ x, const float* __restrict__ p0,
    const float* __restrict__ p1, const float* __restrict__ p2,
    float* __restrict__ xf) {
  __shared__ float tile[32][33];
  const size_t ils  = (size_t)CDIM * CDIM;
  const size_t ils2 = (size_t)CDIM * FFDIM;
  const size_t qkv_ls = (size_t)QKVN * CDIM;
  int r = blockIdx.x;
  if (r < 5184) {                       // wq/wk/wv/wo: 576x576 transposes
    int which = r / 1296, rr = r % 1296;
    int z = rr / 324, rem = rr % 324;
    int bx = rem % 18, by = rem / 18;
    const float* in; bf16* out; size_t ols;
    if (which == 0)      { in = wq; out = wqkvT;                       ols = qkv_ls; }
    else if (which == 1) { in = wk; out = wqkvT + (size_t)CDIM * CDIM; ols = qkv_ls; }
    else if (which == 2) { in = wv; out = wqkvT + (size_t)2 * CDIM * CDIM; ols = qkv_ls; }
    else                 { in = wo; out = woT;                         ols = ils; }
    transpose_body(tile, in, out, CDIM, CDIM, ils, ols, bx, by, z);
  } else if (r < 10368) {               // w1: [576,2304] -> [2304,576]
    int rr = r - 5184;
    int z = rr / 1296, rem = rr % 1296;
    int bx = rem % 72, by = rem / 72;
    transpose_body(tile, w1, w1T, CDIM, FFDIM, ils2, ils2, bx, by, z);
  } else if (r < 15552) {               // w2: [2304,576] -> [576,2304]
    int rr = r - 10368;
    int z = rr / 1296, rem = rr % 1296;
    int bx = rem % 18, by = rem / 18;
    transpose_body(tile, w2, w2T, FFDIM, CDIM, ils2, ils2, bx, by, z);
  } else {                              // build_xf: right_shift(x) + pos
    int idx = (r - 15552) * 256 + threadIdx.x;   // one float4 per thread
    int c4 = idx % 144;
    int s  = (idx / 144) & (S_LEN - 1);
    int b  = idx / (144 * S_LEN);
    int c  = c4 * 4;
    int t = s >> 8, hh = (s >> 4) & 15, w = s & 15;
    float4 pv;
    if (c < 192)       pv = *(const float4*)&p0[t  * 192 + c];
    else if (c < 384)  pv = *(const float4*)&p1[hh * 192 + c - 192];
    else               pv = *(const float4*)&p2[w  * 192 + c - 384];
    float4 xv = make_float4(0.f, 0.f, 0.f, 0.f);
    if (s > 0) xv = *(const float4*)&x[((size_t)b * S_LEN + s - 1) * CDIM + c];
    float4 rr4 = make_float4(xv.x + pv.x, xv.y + pv.y, xv.z + pv.z, xv.w + pv.w);
    *(float4*)&xf[((size_t)b * S_LEN + s) * CDIM + c] = rr4;
  }
}

// ---------------- LayerNorm (eps added to rsqrt, per reference) ----------------
__global__ __launch_bounds__(256) void ln_kernel(
    const float* __restrict__ x, const float* __restrict__ g,
    const float* __restrict__ b, bf16* __restrict__ out) {
  int row  = blockIdx.x * 4 + (threadIdx.x >> 6);
  int lane = threadIdx.x & 63;
  const float* xr = x + (size_t)row * CDIM;
  float vals[9];
  float sum = 0.f;
#pragma unroll
  for (int i = 0; i < 9; i++) { vals[i] = xr[lane + 64 * i]; sum += vals[i]; }
#pragma unroll
  for (int o = 1; o < 64; o <<= 1) sum += __shfl_xor(sum, o);
  float mu = sum * (1.f / CDIM);
  float vs = 0.f;
#pragma unroll
  for (int i = 0; i < 9; i++) { float d = vals[i] - mu; vs += d * d; }
#pragma unroll
  for (int o = 1; o < 64; o <<= 1) vs += __shfl_xor(vs, o);
  float mult = 1e-5f + rsqrtf(vs * (1.f / CDIM));
  bf16* orow = out + (size_t)row * CDIM;
#pragma unroll
  for (int i = 0; i < 9; i++) {
    int c = lane + 64 * i;
    orow[c] = __float2bfloat16((vals[i] - mu) * mult * g[c] + b[c]);
  }
}

// ---------------- GEMM v7: counted-vmcnt pipeline, depth-2 prefetch ----------
// out[M,N] = act(A[M,K] @ Bt[N,K]^T + bias) (+ res)
// 4 LDS buffers; iter t stages tile t+2, then waits vmcnt(2*LPS) so tile t's
// loads have landed while t+1/t+2's stay in flight. ONE raw s_barrier per
// iter. Race safety: iter-t stage writes tile t-2's buffer, whose reads
// finished before barrier(t-1). LDS LINEAR [rows][32] bf16 (64B rows).
template <int BM, int BN, bool BIAS, bool RES, int ACT, bool OUTBF>
__global__ __launch_bounds__(256) void gemm3(
    const bf16* __restrict__ A, const bf16* __restrict__ Bt,
    const float* __restrict__ bias, const float* __restrict__ res,
    void* __restrict__ outp, int N, int K) {
  constexpr int MI = BM / 32;           // m frags per wave
  constexpr int NI = BN / 32;           // n frags per wave
  constexpr int AJ = BM / 64;           // A gload instrs per wave
  constexpr int BJ = BN / 64;           // B gload instrs per wave
  constexpr int LPS = AJ + BJ;          // loads per stage per wave
  __shared__ __align__(16) short ldsA[4][BM * 32];
  __shared__ __align__(16) short ldsB[4][BN * 32];
  const int tid = threadIdx.x, lane = tid & 63, wave = tid >> 6;
  const int lr = lane & 15, quad = lane >> 4;
  const int m0 = blockIdx.x * BM, n0 = blockIdx.y * BN;
  const int wm = (wave & 1) * (BM / 2), wn = (wave >> 1) * (BN / 2);
  f32x4 acc[MI][NI] = {};

  const int srow = lane >> 2, scol = (lane & 3) * 8;
  const short* Ag[AJ];
  int ldsAo[AJ];
#pragma unroll
  for (int j = 0; j < AJ; j++) {
    Ag[j] = (const short*)A + (size_t)(m0 + (wave * AJ + j) * 16 + srow) * K + scol;
    ldsAo[j] = (wave * AJ + j) * 512;
  }
  const short* Bg[BJ];
  int ldsBo[BJ];
#pragma unroll
  for (int j = 0; j < BJ; j++) {
    Bg[j] = (const short*)Bt + (size_t)(n0 + (wave * BJ + j) * 16 + srow) * K + scol;
    ldsBo[j] = (wave * BJ + j) * 512;
  }

  // prologue: stage tiles 0,1 into bufs 0,1 (K >= 64 for all our GEMMs)
#pragma unroll
  for (int j = 0; j < AJ; j++) gload16(Ag[j], &ldsA[0][ldsAo[j]]);
#pragma unroll
  for (int j = 0; j < BJ; j++) gload16(Bg[j], &ldsB[0][ldsBo[j]]);
#pragma unroll
  for (int j = 0; j < AJ; j++) gload16(Ag[j] + 32, &ldsA[1][ldsAo[j]]);
#pragma unroll
  for (int j = 0; j < BJ; j++) gload16(Bg[j] + 32, &ldsB[1][ldsBo[j]]);

  int bi = 0;
  for (int k0 = 0; k0 < K; k0 += 32, bi = (bi + 1) & 3) {
    if (k0 + 64 < K) {                      // tile t+2 exists
      const int sb = (bi + 2) & 3;
#pragma unroll
      for (int j = 0; j < AJ; j++) gload16(Ag[j] + k0 + 64, &ldsA[sb][ldsAo[j]]);
#pragma unroll
      for (int j = 0; j < BJ; j++) gload16(Bg[j] + k0 + 64, &ldsB[sb][ldsBo[j]]);
      wait_vmcnt<2 * LPS>();                // tile t landed; t+1,t+2 in flight
    } else if (k0 + 32 < K) {
      wait_vmcnt<LPS>();                    // tile t landed; t+1 in flight
    } else {
      wait_vmcnt<0>();                      // final tile
    }
    __builtin_amdgcn_s_barrier();           // raw: no implicit vmcnt(0) drain
    __builtin_amdgcn_sched_barrier(0);      // no ds_read hoisting above barrier
    bf16x8 af[MI], bfv[NI];
#pragma unroll
    for (int mi = 0; mi < MI; mi++)
      af[mi] = *(const bf16x8*)&ldsA[bi][(wm + mi * 16 + lr) * 32 + quad * 8];
#pragma unroll
    for (int ni = 0; ni < NI; ni++)
      bfv[ni] = *(const bf16x8*)&ldsB[bi][(wn + ni * 16 + lr) * 32 + quad * 8];
#pragma unroll
    for (int mi = 0; mi < MI; mi++)
#pragma unroll
      for (int ni = 0; ni < NI; ni++)
        acc[mi][ni] = __builtin_amdgcn_mfma_f32_16x16x32_bf16(af[mi], bfv[ni], acc[mi][ni], 0, 0, 0);
  }

  float* fout = (float*)outp;
  bf16*  bout = (bf16*)outp;
#pragma unroll
  for (int mi = 0; mi < MI; mi++)
#pragma unroll
    for (int ni = 0; ni < NI; ni++) {
      int col = n0 + wn + ni * 16 + lr;
#pragma unroll
      for (int r = 0; r < 4; r++) {
        int row = m0 + wm + mi * 16 + quad * 4 + r;
        float v = acc[mi][ni][r];
        if (BIAS) v += bias[col];
        if (ACT == 1) v = v / (1.f + __expf(-1.702f * v));   // GeLU2
        size_t idx = (size_t)row * N + col;
        if (RES) v += res[idx];
        if (OUTBF) bout[idx] = __float2bfloat16(v);
        else       fout[idx] = v;
      }
    }
}

// ---------------- MFMA flash attention v5: defer-max + post-PV reduce --------
__global__ __launch_bounds__(256) void attn_mfma(
    const bf16* __restrict__ qkv, bf16* __restrict__ a) {
  __shared__ __align__(16) short ldsK[2][9 * 512];   // pages: w*2+c (c=0,1), 8=col64 page
  __shared__ __align__(16) short ldsVt[2][80][104];  // [d][key], padded rows
  __shared__ __align__(16) short ldsP[4 * 1024];     // per-wave, fragment-linear
  const int bh = blockIdx.y, b = bh >> 3, h = bh & 7;
  const int tid = threadIdx.x, wave = tid >> 6, lane = tid & 63;
  const int lr = lane & 15, quad = lane >> 4;
  const int qt = (blockIdx.y < 16) ? (15 - (int)blockIdx.x) : (int)blockIdx.x;
  const float scale = 0.11785113019775793f;  // 1/sqrt(72)
  const int qcol = h * DKH, kcol = CDIM + h * DKH, vcol = 2 * CDIM + h * DKH;

  const int qrow = qt * 64 + wave * 16 + lr;
  const short* qg = (const short*)qkv + (size_t)(b * S_LEN + qrow) * QKVN + qcol;
  bf16x8 qfrag[3];
#pragma unroll
  for (int c = 0; c < 3; c++) {
    int d0 = c * 32 + quad * 8;
    bf16x8 z = {0, 0, 0, 0, 0, 0, 0, 0};
    qfrag[c] = (d0 < DKH) ? *(const bf16x8*)(qg + d0) : z;
  }
  f32x4 oacc[5] = {};
  float m[4], l[4];
#pragma unroll
  for (int r = 0; r < 4; r++) { m[r] = -1e30f; l[r] = 0.f; }

  // staging bases (advance by kt*64*QKVN)
  const size_t ktstep = (size_t)64 * QKVN;
  const short* kg0 = (const short*)qkv + (size_t)(b * S_LEN + wave * 16 + lr) * QKVN + kcol + quad * 8;
  const short* kg2 = (const short*)qkv + (size_t)(b * S_LEN + lane) * QKVN + kcol + 64;  // wave0 page-8
  const int vkey = tid & 63, vdgb = tid >> 6;
  const short* vg0 = (const short*)qkv + (size_t)(b * S_LEN + vkey) * QKVN + vcol;

  // ---- prologue: stage kt=0 into buf 0 ----
  {
#pragma unroll
    for (int c = 0; c < 2; c++)
      gload16(kg0 + c * 32, &ldsK[0][(wave * 2 + c) * 512]);
    if (wave == 0) gload16(kg2, &ldsK[0][8 * 512]);
#pragma unroll
    for (int pass = 0; pass < 3; pass++) {
      int d0 = (vdgb + pass * 4) * 8;  // 0..88
      if (d0 < 80) {
        bf16x8 vv = {0, 0, 0, 0, 0, 0, 0, 0};
        if (d0 < DKH) vv = *(const bf16x8*)(vg0 + d0);
#pragma unroll
        for (int j = 0; j < 8; j++) ldsVt[0][d0 + j][vkey] = vv[j];
      }
    }
  }
  __syncthreads();

  for (int kt = 0; kt <= qt; kt++) {
    const int cur = kt & 1, nxt = cur ^ 1;
    const bool pf = (kt < qt);
    bf16x8 vpre[3];
    if (pf) {
      const short* kg = kg0 + (size_t)(kt + 1) * ktstep;
#pragma unroll
      for (int c = 0; c < 2; c++)
        gload16(kg + c * 32, &ldsK[nxt][(wave * 2 + c) * 512]);
      if (wave == 0) gload16(kg2 + (size_t)(kt + 1) * ktstep, &ldsK[nxt][8 * 512]);
      const short* vg = vg0 + (size_t)(kt + 1) * ktstep;
#pragma unroll
      for (int pass = 0; pass < 3; pass++) {
        int d0 = (vdgb + pass * 4) * 8;
        bf16x8 z = {0, 0, 0, 0, 0, 0, 0, 0};
        vpre[pass] = (d0 < DKH) ? *(const bf16x8*)(vg + d0) : z;
      }
    }
    // ---- QK^T ----
    f32x4 sacc[4] = {};
    __builtin_amdgcn_s_setprio(1);
#pragma unroll
    for (int nc = 0; nc < 4; nc++) {
      bf16x8 kf0 = *(const bf16x8*)&ldsK[cur][(nc * 2 + 0) * 512 + lane * 8];
      sacc[nc] = __builtin_amdgcn_mfma_f32_16x16x32_bf16(qfrag[0], kf0, sacc[nc], 0, 0, 0);
      bf16x8 kf1 = *(const bf16x8*)&ldsK[cur][(nc * 2 + 1) * 512 + lane * 8];
      sacc[nc] = __builtin_amdgcn_mfma_f32_16x16x32_bf16(qfrag[1], kf1, sacc[nc], 0, 0, 0);
      bf16x8 kf2 = *(const bf16x8*)&ldsK[cur][8 * 512 + (nc * 16 + lr) * 8];
      sacc[nc] = __builtin_amdgcn_mfma_f32_16x16x32_bf16(qfrag[2], kf2, sacc[nc], 0, 0, 0);
    }
    __builtin_amdgcn_s_setprio(0);
    // ---- scale + causal mask + per-lane local max (no reduce) ----
    float pmax[4];
#pragma unroll
    for (int r = 0; r < 4; r++) pmax[r] = -1e30f;
    bool diag = (kt == qt);
#pragma unroll
    for (int nc = 0; nc < 4; nc++)
#pragma unroll
      for (int r = 0; r < 4; r++) {
        float s = sacc[nc][r] * scale;
        if (diag && (nc * 16 + lr > wave * 16 + quad * 4 + r)) s = -1e30f;
        sacc[nc][r] = s;
        pmax[r] = fmaxf(pmax[r], s);
      }
    // ---- T13 defer-max: rescale only when some lane exceeds m+8 ----
    bool within = (pmax[0] - m[0] <= 8.f) && (pmax[1] - m[1] <= 8.f) &&
                  (pmax[2] - m[2] <= 8.f) && (pmax[3] - m[3] <= 8.f);
    if (!__all(within)) {
      float tmax[4];
#pragma unroll
      for (int r = 0; r < 4; r++) {
        tmax[r] = pmax[r];
        tmax[r] = fmaxf(tmax[r], __shfl_xor(tmax[r], 1));
        tmax[r] = fmaxf(tmax[r], __shfl_xor(tmax[r], 2));
        tmax[r] = fmaxf(tmax[r], __shfl_xor(tmax[r], 4));
        tmax[r] = fmaxf(tmax[r], __shfl_xor(tmax[r], 8));
      }
#pragma unroll
      for (int r = 0; r < 4; r++) {
        float mn = fmaxf(m[r], tmax[r]);
        float alpha = __expf(m[r] - mn);
        m[r] = mn;
        l[r] *= alpha;
#pragma unroll
        for (int dc = 0; dc < 5; dc++) oacc[dc][r] *= alpha;
      }
    }
    // ---- P = exp(s - m), write fragment-linear to ldsP ----
    float psum[4];
#pragma unroll
    for (int r = 0; r < 4; r++) psum[r] = 0.f;
#pragma unroll
    for (int nc = 0; nc < 4; nc++)
#pragma unroll
      for (int r = 0; r < 4; r++) {
        float p = __expf(sacc[nc][r] - m[r]);
        psum[r] += p;
        int col = nc * 16 + lr;
        ldsP[wave * 1024 + (col >> 5) * 512 +
             (((col >> 3) & 3) * 16 + quad * 4 + r) * 8 + (col & 7)] = f2bf_bits(p);
      }
    // ---- PV (P-write -> pfrag-read RAW is compiler-tracked lgkmcnt) ----
    bf16x8 pfrag[2];
#pragma unroll
    for (int kc = 0; kc < 2; kc++)
      pfrag[kc] = *(const bf16x8*)&ldsP[wave * 1024 + kc * 512 + lane * 8];
    __builtin_amdgcn_s_setprio(1);
#pragma unroll
    for (int dc = 0; dc < 5; dc++)
#pragma unroll
      for (int kc = 0; kc < 2; kc++) {
        bf16x8 vf = *(const bf16x8*)&ldsVt[cur][dc * 16 + lr][kc * 32 + quad * 8];
        oacc[dc] = __builtin_amdgcn_mfma_f32_16x16x32_bf16(pfrag[kc], vf, oacc[dc], 0, 0, 0);
      }
    __builtin_amdgcn_s_setprio(0);
    // ---- psum reduce + l update (after PV, off the critical path) ----
#pragma unroll
    for (int r = 0; r < 4; r++) {
      psum[r] += __shfl_xor(psum[r], 1);
      psum[r] += __shfl_xor(psum[r], 2);
      psum[r] += __shfl_xor(psum[r], 4);
      psum[r] += __shfl_xor(psum[r], 8);
      l[r] += psum[r];
    }
    // ---- late V write (prefetched regs -> ldsVt[nxt]) ----
    if (pf) {
#pragma unroll
      for (int pass = 0; pass < 3; pass++) {
        int d0 = (vdgb + pass * 4) * 8;
        if (d0 < 80) {
#pragma unroll
          for (int j = 0; j < 8; j++) ldsVt[nxt][d0 + j][vkey] = vpre[pass][j];
        }
      }
    }
    __syncthreads();
  }  // kt

#pragma unroll
  for (int dc = 0; dc < 5; dc++) {
    int d = dc * 16 + lr;
    if (d < DKH) {
#pragma unroll
      for (int r = 0; r < 4; r++) {
        int row = qt * 64 + wave * 16 + quad * 4 + r;
        float val = oacc[dc][r] / l[r];
        a[(size_t)(b * S_LEN + row) * CDIM + h * DKH + d] = __float2bfloat16(val);
      }
    }
  }
}

// ---------------- launch ----------------
extern "C" void kernel_launch(void* const* d_in, const int* in_sizes, int n_in,
                              void* d_out, int out_size, void* d_ws, size_t ws_size,
                              hipStream_t stream) {
  const float* x    = (const float*)d_in[0];
  const float* pos0 = (const float*)d_in[1];
  const float* pos1 = (const float*)d_in[2];
  const float* pos2 = (const float*)d_in[3];
  const float* ln1g = (const float*)d_in[4];
  const float* ln1b = (const float*)d_in[5];
  const float* wq   = (const float*)d_in[6];
  const float* wk   = (const float*)d_in[7];
  const float* wv   = (const float*)d_in[8];
  const float* wo   = (const float*)d_in[9];
  const float* wob  = (const float*)d_in[10];
  const float* ln2g = (const float*)d_in[11];
  const float* ln2b = (const float*)d_in[12];
  const float* w1   = (const float*)d_in[13];
  const float* b1   = (const float*)d_in[14];
  const float* w2   = (const float*)d_in[15];
  const float* b2   = (const float*)d_in[16];

  char* ws = (char*)d_ws;
  size_t off = 0;
  auto alloc = [&](size_t bytes) {
    char* p = ws + off;
    off += (bytes + 255) & ~(size_t)255;
    return p;
  };
  bf16* wqkvT = (bf16*)alloc((size_t)4 * QKVN * CDIM * sizeof(bf16));
  bf16* woT   = (bf16*)alloc((size_t)4 * CDIM * CDIM * sizeof(bf16));
  bf16* w1T   = (bf16*)alloc((size_t)4 * FFDIM * CDIM * sizeof(bf16));
  bf16* w2T   = (bf16*)alloc((size_t)4 * CDIM * FFDIM * sizeof(bf16));
  bf16* hbuf  = (bf16*)alloc((size_t)MROWS * CDIM * sizeof(bf16));
  bf16* abuf  = (bf16*)alloc((size_t)MROWS * CDIM * sizeof(bf16));
  bf16* ubuf  = (bf16*)alloc((size_t)MROWS * FFDIM * sizeof(bf16));
  bf16* qkvb  = (bf16*)alloc((size_t)MROWS * QKVN * sizeof(bf16));
  float* xf   = (float*)d_out;   // residual stream lives in d_out (fp32)

  const size_t ils  = (size_t)CDIM * CDIM;
  const size_t ils2 = (size_t)CDIM * FFDIM;
  const size_t qkv_ls = (size_t)QKVN * CDIM;

  // single-dispatch prologue: 6 transposes + build_xf (17856 blocks)
  prologue<<<17856, 256, 0, stream>>>(wq, wk, wv, wo, w1, w2,
                                      wqkvT, woT, w1T, w2T,
                                      x, pos0, pos1, pos2, xf);

  for (int l = 0; l < 4; l++) {
    bf16* wqkv_l = wqkvT + (size_t)l * qkv_ls;
    bf16* wo_l   = woT   + (size_t)l * ils;
    bf16* w1_l   = w1T   + (size_t)l * ils2;
    bf16* w2_l   = w2T   + (size_t)l * ils2;

    ln_kernel<<<1024, 256, 0, stream>>>(xf, ln1g + l * CDIM, ln1b + l * CDIM, hbuf);
    // fused QKV: [4096,576] x [1728,576]^T -> qkvb (128x64, 864 blocks)
    gemm3<128, 64, false, false, 0, true><<<dim3(32, QKVN / 64), 256, 0, stream>>>(
        hbuf, wqkv_l, nullptr, nullptr, qkvb, QKVN, CDIM);
    attn_mfma<<<dim3(16, 32), 256, 0, stream>>>(qkvb, abuf);
    // proj + bias + residual -> xf (64x64, 576 blocks)
    gemm3<64, 64, true, true, 0, false><<<dim3(64, CDIM / 64), 256, 0, stream>>>(
        abuf, wo_l, wob + l * CDIM, xf, xf, CDIM, CDIM);
    ln_kernel<<<1024, 256, 0, stream>>>(xf, ln2g + l * CDIM, ln2b + l * CDIM, hbuf);
    // FFN1 + bias + GeLU2 -> ubuf (128x64, 1152 blocks)
    gemm3<128, 64, true, false, 1, true><<<dim3(32, FFDIM / 64), 256, 0, stream>>>(
        hbuf, w1_l, b1 + l * FFDIM, nullptr, ubuf, FFDIM, CDIM);
    // FFN2 + bias + residual -> xf (64x64, 576 blocks)
    gemm3<64, 64, true, true, 0, false><<<dim3(64, CDIM / 64), 256, 0, stream>>>(
        ubuf, w2_l, b2 + l * CDIM, xf, xf, CDIM, FFDIM);
  }
}